// Round 11
// baseline (259.874 us; speedup 1.0000x reference)
//
#include <hip/hip_runtime.h>

#define HW 4096

typedef short bf16x8 __attribute__((ext_vector_type(8)));
typedef float f32x16 __attribute__((ext_vector_type(16)));

__device__ __forceinline__ ushort f2bf_rne(float f) {
    unsigned u = __float_as_uint(f);
    return (ushort)((u + 0x7FFFu + ((u >> 16) & 1u)) >> 16);
}

// ---------------------------------------------------------------------------
// W transpose: Wt[c][o] = W[o][c].  (No counters left anywhere in the
// pipeline -- R11 removed all candidate lists.)
// ---------------------------------------------------------------------------
__global__ __launch_bounds__(256) void transpose_w_kernel(
    const float* __restrict__ Wm, float* __restrict__ Wt)
{
    const int o = blockIdx.x;        // 128
    const int c = threadIdx.x;       // 256
    Wt[c * 128 + o] = Wm[o * 256 + c];
}

// ---------------------------------------------------------------------------
// Kernel 1: 1x1-conv projection as LDS-tiled vector GEMM (R8 structure,
// outputs bitwise-identical to R8-R10).  best[] zero-init folded in.
// Outputs: Qt/Pt fp32 [b][n][128], qnorm, bf16 packs in 32x32x16 fragment
// order: PK[b][t32][ks][lt][j] = proj[c=ks*16+(lt>>5)*8+j][n=t32*32+(lt&31)].
// ---------------------------------------------------------------------------
__global__ __launch_bounds__(256) void proj_kernel(
    const float* __restrict__ Fq, const float* __restrict__ Fp,
    const float* __restrict__ Wt, const float* __restrict__ bias,
    float* __restrict__ Qt, float* __restrict__ Pt,
    ushort* __restrict__ Qpk, ushort* __restrict__ Ppk,
    float* __restrict__ qnorm, unsigned long long* __restrict__ best)
{
    __shared__ float Ws[64][128];    // 32 KB
    __shared__ float Xs[64][64];     // 16 KB
    __shared__ float psum[16][68];

    const int tid = threadIdx.x;
    const int z  = blockIdx.z;                 // 0: q, 1: p
    const float* __restrict__ X = z ? Fp : Fq;
    const int b  = blockIdx.y;
    const int n0 = blockIdx.x * 64;
    const int og = tid >> 4;                   // 8 o's
    const int ng = tid & 15;                   // 4 n's

    float acc[4][8];
    #pragma unroll
    for (int i = 0; i < 4; ++i)
        #pragma unroll
        for (int j = 0; j < 8; ++j) acc[i][j] = 0.f;

    for (int cc = 0; cc < 4; ++cc) {
        __syncthreads();
        {
            const float4* src = (const float4*)(Wt + (size_t)cc * 64 * 128);
            float4* dst = (float4*)Ws;
            #pragma unroll
            for (int it = 0; it < 8; ++it) dst[it * 256 + tid] = src[it * 256 + tid];
        }
        #pragma unroll
        for (int it = 0; it < 4; ++it) {
            int f = it * 256 + tid;
            int r = f >> 4, n4 = f & 15;
            *(float4*)&Xs[r][n4 * 4] =
                *(const float4*)&X[(size_t)(b * 256 + cc * 64 + r) * HW + n0 + n4 * 4];
        }
        __syncthreads();

        for (int r = 0; r < 64; ++r) {
            float4 w0 = *(const float4*)&Ws[r][og * 8];
            float4 w1 = *(const float4*)&Ws[r][og * 8 + 4];
            float4 xv = *(const float4*)&Xs[r][ng * 4];
            float wa[8] = {w0.x, w0.y, w0.z, w0.w, w1.x, w1.y, w1.z, w1.w};
            float xa[4] = {xv.x, xv.y, xv.z, xv.w};
            #pragma unroll
            for (int i = 0; i < 4; ++i)
                #pragma unroll
                for (int j = 0; j < 8; ++j)
                    acc[i][j] += wa[j] * xa[i];
        }
    }

    {
        float4 b0 = *(const float4*)&bias[og * 8];
        float4 b1 = *(const float4*)&bias[og * 8 + 4];
        float ba[8] = {b0.x, b0.y, b0.z, b0.w, b1.x, b1.y, b1.z, b1.w};
        #pragma unroll
        for (int i = 0; i < 4; ++i)
            #pragma unroll
            for (int j = 0; j < 8; ++j) acc[i][j] += ba[j];
    }

    #pragma unroll
    for (int i = 0; i < 4; ++i) {
        float s = 0.f;
        #pragma unroll
        for (int j = 0; j < 8; ++j) s += acc[i][j] * acc[i][j];
        psum[og][ng * 4 + i] = s;
    }
    __syncthreads();
    float tot[4];
    #pragma unroll
    for (int i = 0; i < 4; ++i) {
        float s = 0.f;
        #pragma unroll
        for (int g = 0; g < 16; ++g) s += psum[g][ng * 4 + i];
        tot[i] = s;
    }

    if (z) {
        #pragma unroll
        for (int i = 0; i < 4; ++i) {
            float s = 1.0f / sqrtf(tot[i]);
            #pragma unroll
            for (int j = 0; j < 8; ++j) acc[i][j] *= s;
        }
    } else {
        if (og == 0) {
            #pragma unroll
            for (int i = 0; i < 4; ++i)
                qnorm[b * HW + n0 + ng * 4 + i] = sqrtf(tot[i]);
        }
        if (og == 1) {
            #pragma unroll
            for (int i = 0; i < 4; ++i)
                best[(size_t)b * HW + n0 + ng * 4 + i] = 0ull;
        }
    }

    {
        float* __restrict__ T = z ? Pt : Qt;
        #pragma unroll
        for (int i = 0; i < 4; ++i) {
            size_t tb = ((size_t)b * HW + n0 + ng * 4 + i) * 128 + og * 8;
            *(float4*)&T[tb]     = make_float4(acc[i][0], acc[i][1], acc[i][2], acc[i][3]);
            *(float4*)&T[tb + 4] = make_float4(acc[i][4], acc[i][5], acc[i][6], acc[i][7]);
        }
    }
    {
        ushort* __restrict__ PK = z ? Ppk : Qpk;
        const int ks = og >> 1;
        #pragma unroll
        for (int i = 0; i < 4; ++i) {
            const int na  = n0 + ng * 4 + i;
            const int t32 = na >> 5;
            const int lt  = (na & 31) + 32 * (og & 1);
            ushort u[8];
            #pragma unroll
            for (int k = 0; k < 8; ++k) u[k] = f2bf_rne(acc[i][k]);
            size_t pk = ((((size_t)b * 128 + t32) * 8 + ks) * 64 + lt) * 8;
            uint4 w;
            w.x = (unsigned)u[0] | ((unsigned)u[1] << 16);
            w.y = (unsigned)u[2] | ((unsigned)u[3] << 16);
            w.z = (unsigned)u[4] | ((unsigned)u[5] << 16);
            w.w = (unsigned)u[6] | ((unsigned)u[7] << 16);
            *(uint4*)&PK[pk] = w;
        }
    }
}

// ---------------------------------------------------------------------------
// SINGLE MFMA pass: per-(n, 128-m-chunk) bf16 maxima.  Grid (32,4,8):
// block = 128 n x 512 m (4 chunks of 128).  bestv[16 r][4 ch] register banks
// (ch is unroll-uniform -> static index, plain fmax, ZERO per-chunk cross-
// lane work -- the R10 killer).  ONE final 5-level shuffle reduce of 64
// values, then Vg[b][n][32] (global 128-m chunk index = ms*4+ch).
// D mapping: m = lane&31, row = (r&3)+8*(r>>2)+4*(lane>>5).
// ---------------------------------------------------------------------------
__global__ __launch_bounds__(256, 2) void sim_max_kernel(
    const ushort* __restrict__ Qpk, const ushort* __restrict__ Ppk,
    float* __restrict__ Vg)
{
    __shared__ ushort Qs[16384];   // 32 KB
    __shared__ ushort Bs[16384];   // 32 KB

    const int tid  = threadIdx.x;
    const int lane = tid & 63;
    const int w    = tid >> 6;
    const int nb   = blockIdx.x;   // 32
    const int b    = blockIdx.y;   // 4
    const int ms   = blockIdx.z;   // 8 -> m in [ms*512, ms*512+512)

    {
        const uint4* src = (const uint4*)(Qpk + ((size_t)b * 128 + nb * 4) * 4096);
        uint4* dst = (uint4*)Qs;
        #pragma unroll
        for (int it = 0; it < 8; ++it) dst[it * 256 + tid] = src[it * 256 + tid];
    }
    __syncthreads();

    bf16x8 af[8];
    #pragma unroll
    for (int ks = 0; ks < 8; ++ks)
        af[ks] = *(const bf16x8*)&Qs[((w * 8 + ks) * 64 + lane) * 8];

    float bestv[16][4];
    #pragma unroll
    for (int r = 0; r < 16; ++r)
        #pragma unroll
        for (int ch = 0; ch < 4; ++ch) bestv[r][ch] = -1e30f;

    #pragma unroll 1
    for (int ch = 0; ch < 4; ++ch) {
        __syncthreads();
        {
            const uint4* src = (const uint4*)(Ppk +
                ((size_t)b * 128 + ms * 16 + ch * 4) * 4096);
            uint4* dst = (uint4*)Bs;
            #pragma unroll
            for (int it = 0; it < 8; ++it) dst[it * 256 + tid] = src[it * 256 + tid];
        }
        __syncthreads();

        #pragma unroll
        for (int mtl = 0; mtl < 4; ++mtl) {
            f32x16 acc;
            #pragma unroll
            for (int r = 0; r < 16; ++r) acc[r] = 0.f;
            #pragma unroll
            for (int ks = 0; ks < 8; ++ks) {
                bf16x8 bb = *(const bf16x8*)&Bs[((mtl * 8 + ks) * 64 + lane) * 8];
                acc = __builtin_amdgcn_mfma_f32_32x32x16_bf16(af[ks], bb, acc, 0, 0, 0);
            }
            #pragma unroll
            for (int r = 0; r < 16; ++r)
                bestv[r][ch] = fmaxf(bestv[r][ch], acc[r]);
        }
    }

    // one final reduce: 64 independent 5-chains (pipelineable, no side effects)
    #pragma unroll
    for (int ch = 0; ch < 4; ++ch) {
        #pragma unroll
        for (int r = 0; r < 16; ++r) {
            float v = bestv[r][ch];
            #pragma unroll
            for (int d = 1; d < 32; d <<= 1)
                v = fmaxf(v, __shfl_xor(v, d, 64));
            if ((lane & 31) == 0) {
                int nl_ = (r & 3) + 8 * (r >> 2) + 4 * (lane >> 5);
                int na = nb * 128 + w * 32 + nl_;
                Vg[((size_t)b * HW + na) * 32 + ms * 4 + ch] = v;
            }
        }
    }
}

// ---------------------------------------------------------------------------
// mask: thr[n] = max_ch Vg - (0.016||q||+1e-6);  mask32[n] = bits of chunks
// with Vg >= thr.  Soundness (validated margin algebra): np's argmax m* has
// s_bf16(m*) >= gmax_bf16 - 2*delta >= thr, so its chunk bit is always set.
// ---------------------------------------------------------------------------
__global__ __launch_bounds__(256) void mask_kernel(
    const float* __restrict__ Vg, const float* __restrict__ qnorm,
    unsigned* __restrict__ mask)
{
    int i = blockIdx.x * 256 + threadIdx.x;   // 16384
    float v[32];
    #pragma unroll
    for (int j = 0; j < 32; j += 4)
        *(float4*)&v[j] = *(const float4*)&Vg[(size_t)i * 32 + j];
    float g = v[0];
    #pragma unroll
    for (int j = 1; j < 32; ++j) g = fmaxf(g, v[j]);
    float thr = g - (0.016f * qnorm[i] + 1e-6f);
    unsigned mk = 0u;
    #pragma unroll
    for (int j = 0; j < 32; ++j) mk |= (v[j] >= thr) ? (1u << j) : 0u;
    mask[i] = mk;
}

// ---------------------------------------------------------------------------
// rescore as dense mini-GEMM.  Block (ch, b, half): m-range = ch*128+half*64
// + [0,64).  Phase 1: scan mask bit ch -> LDS n-list (cap 4096 = complete,
// no overflow possible).  Phase 2: stage P [128c][64m] fp32 (transposed,
// stride 68 for alignment).  Phase 3: batches of 64 n: stage q rows
// ([n][c], stride 132), 16x16 thread grid, 4n x 4m register tiles; exact
// sequential-c fp32 accumulation (matches np).  Per-n argmax via u64 keys
// (orderedbits(v)<<32 | 4095-m  ->  max value, tie -> smallest m), 4-level
// shuffle over the 16 m-threads, atomicMax into best (distinct addresses).
// ---------------------------------------------------------------------------
__global__ __launch_bounds__(256) void rescore_kernel(
    const float* __restrict__ Qt, const float* __restrict__ Pt,
    const unsigned* __restrict__ mask,
    unsigned long long* __restrict__ best)
{
    __shared__ ushort lst[4096];        // 8 KB
    __shared__ float Ps[128 * 68];      // 34.8 KB  [c][m] stride 68
    __shared__ float Qs2[64 * 132];     // 33.8 KB  [n][c] stride 132
    __shared__ unsigned lcnt;

    const int tid  = threadIdx.x;
    const int ch   = blockIdx.x;   // 32
    const int b    = blockIdx.y;   // 4
    const int half = blockIdx.z;   // 2
    const int mbase = ch * 128 + half * 64;

    if (tid == 0) lcnt = 0u;
    __syncthreads();

    for (int n = tid; n < 4096; n += 256)
        if ((mask[b * 4096 + n] >> ch) & 1u) {
            unsigned pos = atomicAdd(&lcnt, 1u);
            lst[pos] = (ushort)n;
        }
    __syncthreads();
    const unsigned cnt = lcnt;
    if (cnt == 0) return;

    // stage P half-chunk, transposed to [c][m]
    #pragma unroll
    for (int it = 0; it < 8; ++it) {
        int f = it * 256 + tid;        // 2048 = 64 m x 32 c4
        int m = f >> 5, c4 = f & 31;
        float4 pv = *(const float4*)&Pt[((size_t)b * HW + mbase + m) * 128 + c4 * 4];
        Ps[(c4 * 4 + 0) * 68 + m] = pv.x;
        Ps[(c4 * 4 + 1) * 68 + m] = pv.y;
        Ps[(c4 * 4 + 2) * 68 + m] = pv.z;
        Ps[(c4 * 4 + 3) * 68 + m] = pv.w;
    }

    const int tx  = tid & 15;      // m: 4 each
    const int tyy = tid >> 4;      // n: 4 each

    for (unsigned base = 0; base < cnt; base += 64) {
        __syncthreads();   // protect prior batch's Qs2 reads (first: P stage done)
        #pragma unroll
        for (int it = 0; it < 8; ++it) {
            int f = it * 256 + tid;    // 2048 = 64 slots x 32 c4
            int slot = f >> 5, c4 = f & 31;
            unsigned sl = base + slot;
            int n = lst[sl < cnt ? sl : (cnt - 1)];
            *(float4*)&Qs2[slot * 132 + c4 * 4] =
                *(const float4*)&Qt[((size_t)b * HW + n) * 128 + c4 * 4];
        }
        __syncthreads();

        float acc[4][4];
        #pragma unroll
        for (int i = 0; i < 4; ++i)
            #pragma unroll
            for (int j = 0; j < 4; ++j) acc[i][j] = 0.f;

        for (int c = 0; c < 128; ++c) {
            float4 pv = *(const float4*)&Ps[c * 68 + tx * 4];
            float pa[4] = {pv.x, pv.y, pv.z, pv.w};
            #pragma unroll
            for (int i = 0; i < 4; ++i) {
                float qv = Qs2[(tyy * 4 + i) * 132 + c];
                #pragma unroll
                for (int j = 0; j < 4; ++j)
                    acc[i][j] += qv * pa[j];
            }
        }

        #pragma unroll
        for (int i = 0; i < 4; ++i) {
            // in-thread best over 4 m (u64 key: max value, tie -> smaller m)
            unsigned long long key = 0ull;
            #pragma unroll
            for (int j = 0; j < 4; ++j) {
                unsigned u = __float_as_uint(acc[i][j]);
                unsigned kk = (u & 0x80000000u) ? ~u : (u | 0x80000000u);
                int m = mbase + tx * 4 + j;
                unsigned long long kj = ((unsigned long long)kk << 32) |
                                        (unsigned)(4095 - m);
                if (kj > key) key = kj;
            }
            // reduce over the 16 m-threads (lane bits 0..3)
            #pragma unroll
            for (int d = 1; d < 16; d <<= 1) {
                unsigned lo = (unsigned)key, hi = (unsigned)(key >> 32);
                unsigned olo = __shfl_xor(lo, d, 64);
                unsigned ohi = __shfl_xor(hi, d, 64);
                unsigned long long ok = ((unsigned long long)ohi << 32) | olo;
                if (ok > key) key = ok;
            }
            unsigned sl = base + tyy * 4 + i;
            if (tx == 0 && sl < cnt) {
                int n = lst[sl];
                atomicMax(&best[(size_t)b * HW + n], key);
            }
        }
    }
}

// ---------------------------------------------------------------------------
// gather: out[b][c][n] = Fp[b][c][m(n)]; stage each 16 KB Fp row in LDS.
// ---------------------------------------------------------------------------
__global__ __launch_bounds__(256) void gather_kernel(
    const float* __restrict__ Fp, const unsigned long long* __restrict__ best,
    float* __restrict__ out)
{
    __shared__ float row[4096];
    const int blk = blockIdx.x;      // 1024 = 4b x 256c
    const int c = blk & 255;
    const int b = blk >> 8;
    const int tid = threadIdx.x;

    const float* __restrict__ src = Fp + ((size_t)b * 256 + c) * HW;
    #pragma unroll
    for (int it = 0; it < 4; ++it) {
        int f = it * 256 + tid;
        *(float4*)&row[f * 4] = *(const float4*)&src[f * 4];
    }
    __syncthreads();

    float* __restrict__ dst = out + ((size_t)b * 256 + c) * HW;
    #pragma unroll
    for (int it = 0; it < 16; ++it) {
        int n = it * 256 + tid;
        int m = 4095 - (int)(best[(size_t)b * HW + n] & 0xFFFull);
        dst[n] = row[m];
    }
}

extern "C" void kernel_launch(void* const* d_in, const int* in_sizes, int n_in,
                              void* d_out, int out_size, void* d_ws, size_t ws_size,
                              hipStream_t stream) {
    const float* Fq   = (const float*)d_in[0];
    const float* Fp   = (const float*)d_in[1];
    const float* Wm   = (const float*)d_in[2];
    const float* bias = (const float*)d_in[3];
    float* out = (float*)d_out;

    char* base = (char*)d_ws;
    float*  Qt    = (float*)(base);                               // 8 MB
    float*  Pt    = (float*)(base + (8u << 20));                  // 8 MB
    ushort* Qpk   = (ushort*)(base + (16u << 20));                // 4 MB
    ushort* Ppk   = (ushort*)(base + (20u << 20));                // 4 MB
    char* x = base + (24u << 20);
    float*  qnorm = (float*)x;              x += 65536;           // 64 KB
    unsigned long long* best = (unsigned long long*)x; x += 131072; // 128 KB
    float*  Vg    = (float*)x;              x += (size_t)16384 * 32 * 4; // 2 MB
    unsigned* mask = (unsigned*)x;          x += 65536;           // 64 KB
    float*  Wtg   = (float*)x;                                    // 128 KB

    transpose_w_kernel<<<128, 256, 0, stream>>>(Wm, Wtg);
    proj_kernel<<<dim3(64, 4, 2), 256, 0, stream>>>(Fq, Fp, Wtg, bias,
                                                    Qt, Pt, Qpk, Ppk, qnorm, best);
    sim_max_kernel<<<dim3(32, 4, 8), 256, 0, stream>>>(Qpk, Ppk, Vg);
    mask_kernel<<<64, 256, 0, stream>>>(Vg, qnorm, mask);
    rescore_kernel<<<dim3(32, 4, 2), 256, 0, stream>>>(Qt, Pt, mask, best);
    gather_kernel<<<1024, 256, 0, stream>>>(Fp, best, out);
}